// Round 2
// baseline (1454.688 us; speedup 1.0000x reference)
//
#include <hip/hip_runtime.h>
#include <hip/hip_bf16.h>
#include <math.h>

#define BB 64
#define TT 128
#define MM 256
#define DD 256
#define NB 4

// One block per batch element; 1024 threads = 16 waves.
// Thread t: c = t>>8 (k-quarter), jj = t&255 (output row). Holds proc_W[jj][64c..64c+63]
// in 64 VGPRs permanently. All other per-row constants live in LDS to keep
// VGPR <= 128 (required for a 16-wave block to be resident).
__global__ __launch_bounds__(1024, 1)
void swarm_kernel(const float* __restrict__ x,        // [B,T,8]
                  const float* __restrict__ in_W,     // [D,8]
                  const float* __restrict__ in_b,     // [D]
                  const float* __restrict__ out_W,    // [8,D]
                  const float* __restrict__ out_b,    // [8]
                  const float* __restrict__ proc_W,   // [1,D,D]
                  const float* __restrict__ proc_b,   // [1,D]
                  const float* __restrict__ dest,     // [N,M]
                  const float* __restrict__ jg_W,     // [N,1,D]
                  const float* __restrict__ jg_b,     // [N,1]
                  const float* __restrict__ ctx_strength, // [N]
                  const float* __restrict__ phase,    // [N,16]
                  const float* __restrict__ ptr_init, // [N,B]
                  float* __restrict__ out,            // [B,T,8]
                  float* __restrict__ ws)             // ring: B*M*D floats
{
  const int b    = blockIdx.x;
  const int tid  = threadIdx.x;
  const int wave = tid >> 6;
  const int lane = tid & 63;
  const int c    = tid >> 8;     // 0..3  (k-quarter)
  const int jj   = tid & 255;    // 0..255 (output row)
  const bool j256 = (tid < 256);
  const int j = tid;             // valid row index when j256

  float* __restrict__ ring = ws + (size_t)b * (MM * DD);

  __shared__ __align__(16) float s_lds[DD];
  __shared__ float part_lds[4 * DD];
  __shared__ float hid_lds[NB * DD];
  __shared__ float red_lds[4];
  __shared__ float red2_lds[32];
  __shared__ float ptr_lds[NB];
  // per-row constants (register-diet: keep them out of VGPRs)
  __shared__ float cst_inWT[8 * DD];   // in_W transposed: [cc][j]
  __shared__ float cst_inb[DD];
  __shared__ float cst_pb[DD];
  __shared__ float cst_jgW[NB * DD];
  __shared__ float cst_ph[NB * DD];    // 0.1*phase padded to D
  __shared__ float cst_outW[8 * DD];   // out_W as-is [o][j]
  __shared__ float cst_sig[NB];
  __shared__ float cst_jgb[NB];

  // ---- distribute proc_W into registers: Wreg[kk] = W[jj][c*64+kk] ----
  float Wreg[64];
  {
    const float4* src = (const float4*)(proc_W + (size_t)jj * DD + c * 64);
    #pragma unroll
    for (int q = 0; q < 16; ++q) {
      float4 v = src[q];
      Wreg[4*q+0] = v.x; Wreg[4*q+1] = v.y; Wreg[4*q+2] = v.z; Wreg[4*q+3] = v.w;
    }
  }

  // ---- load constants into LDS ----
  for (int i = tid; i < 8 * DD; i += 1024) {
    int cc = i >> 8, jx = i & 255;
    cst_inWT[i] = in_W[jx * 8 + cc];      // transpose
    cst_outW[i] = out_W[i];               // [8,D] flat, same layout
  }
  {
    int i = tid;                           // NB*DD == 1024 exactly
    int n = i >> 8, jx = i & 255;
    cst_jgW[i] = jg_W[i];                  // [N,1,D] flat
    cst_ph[i]  = (jx < 16) ? 0.1f * phase[n * 16 + jx] : 0.f;
    hid_lds[i] = 0.f;
  }
  if (j256) { cst_inb[j] = in_b[j]; cst_pb[j] = proc_b[j]; }
  if (tid < NB) {
    cst_sig[tid] = 1.f / (1.f + expf(-ctx_strength[tid]));
    cst_jgb[tid] = jg_b[tid];
    ptr_lds[tid] = ptr_init[tid * BB + b];
  }

  // ---- zero ring (ws is poisoned 0xAA before every launch) ----
  {
    float4 z4 = make_float4(0.f, 0.f, 0.f, 0.f);
    float4* r4 = (float4*)ring;
    #pragma unroll
    for (int q = 0; q < (MM * DD / 4) / 1024; ++q)
      r4[q * 1024 + tid] = z4;
  }
  __syncthreads();

  for (int t = 0; t < TT; ++t) {
    // shared input projection for this step (once, reused by all 4 beings)
    float inp_r = 0.f;
    if (j256) {
      const float* xt = x + ((size_t)b * TT + t) * 8;
      float a = cst_inb[j];
      #pragma unroll
      for (int cc = 0; cc < 8; ++cc) a = fmaf(xt[cc], cst_inWT[cc * DD + j], a);
      inp_r = a;
    }
    float sacc = 0.f;   // sum over beings of s2[j], for the mean output

    #pragma unroll
    for (int n = 0; n < NB; ++n) {
      float p = 0.f, w5[5];
      int basei = 0;

      // ---- phase A (waves 0-3): window weights, ring gather, pre-activation ----
      if (j256) {
        p = ptr_lds[n];
        basei = (int)floorf(p);
        if (basei < 0) basei = 0;
        if (basei > MM - 1) basei = MM - 1;
        float v5[5], mx = -1e30f;
        #pragma unroll
        for (int i = 0; i < 5; ++i) {
          int idx = (basei + i - 2 + MM) & (MM - 1);
          float d = (float)idx - p + 128.f;
          d -= 256.f * floorf(d * (1.f / 256.f));   // jnp.mod(d,256)
          float del = d - 128.f;
          v5[i] = -(del * del) * 0.125f;            // -(delta^2)/TEMP
          mx = fmaxf(mx, v5[i]);
        }
        float se = 0.f;
        #pragma unroll
        for (int i = 0; i < 5; ++i) { w5[i] = expf(v5[i] - mx); se += w5[i]; }
        float inv = 1.f / se;
        float ctx = 0.f;
        #pragma unroll
        for (int i = 0; i < 5; ++i) {
          w5[i] *= inv;
          int idx = (basei + i - 2 + MM) & (MM - 1);
          ctx = fmaf(w5[i], ring[idx * DD + j], ctx);
        }
        float comb = inp_r + cst_sig[n] * ctx + cst_ph[n * DD + j];
        s_lds[j] = tanhf(comb + hid_lds[n * DD + j]);
      }
      __syncthreads();

      // ---- phase B (all 16 waves): matvec partials from register-resident W ----
      {
        float a0 = 0.f, a1 = 0.f, a2 = 0.f, a3 = 0.f;
        const float4* s4 = (const float4*)(s_lds + c * 64);
        #pragma unroll
        for (int q = 0; q < 16; ++q) {
          float4 sv = s4[q];                          // wave-uniform LDS broadcast
          a0 = fmaf(Wreg[4*q+0], sv.x, a0);
          a1 = fmaf(Wreg[4*q+1], sv.y, a1);
          a2 = fmaf(Wreg[4*q+2], sv.z, a2);
          a3 = fmaf(Wreg[4*q+3], sv.w, a3);
        }
        part_lds[c * DD + jj] = (a0 + a1) + (a2 + a3);
      }
      __syncthreads();

      // ---- phase C (waves 0-3): combine, s2, ring RMW, jump-gate partials ----
      if (j256) {
        float sum = ((part_lds[j] + part_lds[DD + j]) +
                     (part_lds[2 * DD + j] + part_lds[3 * DD + j])) + cst_pb[j];
        float s2 = tanhf(sum);
        hid_lds[n * DD + j] = s2;
        sacc += s2;
        // ring column j is thread-private: re-read (L1-hot) instead of
        // carrying nb5[5] in registers across the matvec.
        #pragma unroll
        for (int i = 0; i < 5; ++i) {
          int idx = (basei + i - 2 + MM) & (MM - 1);
          float* rp = ring + idx * DD + j;
          *rp = *rp + w5[i] * s2;                     // gaussian-weighted write
        }
        float v = s2 * cst_jgW[n * DD + j];
        #pragma unroll
        for (int off = 32; off > 0; off >>= 1) v += __shfl_down(v, off, 64);
        if (lane == 0) red_lds[wave] = v;
      }
      __syncthreads();

      // ---- phase D: finalize jump gate, update pointer ----
      if (j256) {
        float jl = ((red_lds[0] + red_lds[1]) + (red_lds[2] + red_lds[3])) + cst_jgb[n];
        if (tid == 0) {
          float dstv = dest[n * MM + basei];
          float walk = p + 1.f;
          if (walk >= 256.f) walk -= 256.f;           // jnp.mod(p+1, M)
          ptr_lds[n] = (jl > 0.f) ? dstv : walk;      // hard gate: pr>0.5 <=> jl>0
        }
      }
      // no barrier needed: next phase A touches neither red_lds nor ptr_lds[n]
    } // beings

    // ---- output: combined[o] = out_b[o] + 0.25 * sum_j sacc[j]*out_W[o][j] ----
    if (j256) {
      #pragma unroll
      for (int o = 0; o < 8; ++o) {
        float v = sacc * cst_outW[o * DD + j];
        #pragma unroll
        for (int off = 32; off > 0; off >>= 1) v += __shfl_down(v, off, 64);
        if (lane == 0) red2_lds[o * 4 + wave] = v;
      }
    }
    __syncthreads();
    if (tid < 8) {
      float s = (red2_lds[tid * 4 + 0] + red2_lds[tid * 4 + 1]) +
                (red2_lds[tid * 4 + 2] + red2_lds[tid * 4 + 3]);
      out[((size_t)b * TT + t) * 8 + tid] = out_b[tid] + 0.25f * s;
    }
    __syncthreads();
  } // t
}

extern "C" void kernel_launch(void* const* d_in, const int* in_sizes, int n_in,
                              void* d_out, int out_size, void* d_ws, size_t ws_size,
                              hipStream_t stream) {
  const float* x        = (const float*)d_in[0];
  const float* in_W     = (const float*)d_in[1];
  const float* in_b     = (const float*)d_in[2];
  const float* out_W    = (const float*)d_in[3];
  const float* out_b    = (const float*)d_in[4];
  const float* proc_W   = (const float*)d_in[5];
  const float* proc_b   = (const float*)d_in[6];
  const float* dest     = (const float*)d_in[7];
  const float* jg_W     = (const float*)d_in[8];
  const float* jg_b     = (const float*)d_in[9];
  const float* ctx_s    = (const float*)d_in[10];
  const float* phase    = (const float*)d_in[11];
  const float* ptr_init = (const float*)d_in[12];
  float* outp = (float*)d_out;
  float* ws   = (float*)d_ws;

  hipLaunchKernelGGL(swarm_kernel, dim3(BB), dim3(1024), 0, stream,
                     x, in_W, in_b, out_W, out_b, proc_W, proc_b, dest,
                     jg_W, jg_b, ctx_s, phase, ptr_init, outp, ws);
}